// Round 16
// baseline (183.665 us; speedup 1.0000x reference)
//
#include <hip/hip_runtime.h>
#include <hip/hip_bf16.h>

typedef __hip_bfloat16 bf16;
typedef _Float16 h16;
typedef __attribute__((ext_vector_type(2))) _Float16 h16x2;
typedef __attribute__((ext_vector_type(2))) __fp16 fp16x2;
typedef __attribute__((ext_vector_type(8))) _Float16 h16x8;
typedef __attribute__((ext_vector_type(4))) float f32x4;
typedef __attribute__((ext_vector_type(16))) float f32x16;

__device__ __forceinline__ float lrelu(float x) { return fmaxf(x, 0.1f * x); }
__device__ __forceinline__ float ldE(const void* p, long i, int f32) {
    return f32 ? ((const float*)p)[i] : __bfloat162float(((const bf16*)p)[i]);
}
// Packed epilogue: f32x4 -> lrelu -> 4 h16 in a uint2 (cvt_pkrtz + v_pk ops).
__device__ __forceinline__ uint2 pk4l(float a, float b, float c, float d) {
    union { fp16x2 f; h16x2 h; } lo, hi;
    lo.f = __builtin_amdgcn_cvt_pkrtz(a, b);
    hi.f = __builtin_amdgcn_cvt_pkrtz(c, d);
    const h16x2 cl = {(h16)0.1f, (h16)0.1f};
    h16x2 lo2 = __builtin_elementwise_max(lo.h, lo.h * cl);
    h16x2 hi2 = __builtin_elementwise_max(hi.h, hi.h * cl);
    union { h16x2 h[2]; uint2 u; } t;
    t.h[0] = lo2; t.h[1] = hi2;
    return t.u;
}
// lane^1 swap on the VALU pipe (DPP quad_perm [1,0,3,2]) — not the LDS pipe.
__device__ __forceinline__ uint2 dpp_xor1(uint2 v) {
    uint2 r;
    r.x = (unsigned)__builtin_amdgcn_mov_dpp((int)v.x, 0xB1, 0xF, 0xF, true);
    r.y = (unsigned)__builtin_amdgcn_mov_dpp((int)v.y, 0xB1, 0xF, 0xF, true);
    return r;
}
__device__ __forceinline__ uint2 pkmax2(uint2 a, uint2 b) {
    union { unsigned u; h16x2 h; } ax, ay, bx, by, rx, ry;
    ax.u = a.x; ay.u = a.y; bx.u = b.x; by.u = b.y;
    rx.h = __builtin_elementwise_max(ax.h, bx.h);
    ry.h = __builtin_elementwise_max(ay.h, by.h);
    uint2 r; r.x = rx.u; r.y = ry.u;
    return r;
}
__device__ __forceinline__ unsigned umx(unsigned a, unsigned b) { return a > b ? a : b; }
// Compiler-only ordering barrier: wave-private buffers + in-order DS pipe
// (validated round 9).
#define LDS_FENCE() asm volatile("" ::: "memory")

// ---------------- workspace layout ----------------
// float region (wsf):
//   [0..63] qw1 plain [co*4+ci*2+dk]
//   [64..79] fb1 [80..95] fb2 [96..127] fb3 [128..159] fb4
//   [160..223] fbd [224..287] qwo [288] fbo   int flag @ index 290
// f16 frag region wh = (h16*)(wsf+292):
//   F2 @0 (1024), F3 @1024 (2560), F4 @3584 (5120), FD @8704 (55296)

__device__ __forceinline__ float qv(const void* src, int idx, float sc, int f32) {
    float w = ldE(src, idx, f32);
    float q = rintf(w / sc);                    // round-half-even like jnp.round
    return fminf(127.f, fmaxf(-127.f, q)) * sc; // clip then dequant
}

__device__ float block_scale(const void* src, int n, int f32, int tid, float* red) {
    unsigned m = 0;
    const uint4* p = (const uint4*)src;
    if (f32) {
        int nv = n >> 2;
        for (int i = tid; i < nv; i += 256) {
            uint4 u = p[i];
            m = umx(m, u.x & 0x7FFFFFFFu); m = umx(m, u.y & 0x7FFFFFFFu);
            m = umx(m, u.z & 0x7FFFFFFFu); m = umx(m, u.w & 0x7FFFFFFFu);
        }
        union { unsigned u; float f; } c; c.u = m;
        red[tid] = c.f;
    } else {
        int nv = n >> 3;
        for (int i = tid; i < nv; i += 256) {
            uint4 u = p[i];
            unsigned a;
            a = u.x & 0x7FFF7FFFu; m = umx(m, a >> 16); m = umx(m, a & 0xFFFFu);
            a = u.y & 0x7FFF7FFFu; m = umx(m, a >> 16); m = umx(m, a & 0xFFFFu);
            a = u.z & 0x7FFF7FFFu; m = umx(m, a >> 16); m = umx(m, a & 0xFFFFu);
            a = u.w & 0x7FFF7FFFu; m = umx(m, a >> 16); m = umx(m, a & 0xFFFFu);
        }
        union { unsigned u; float f; } c; c.u = m << 16;
        red[tid] = c.f;
    }
    __syncthreads();
    for (int s = 128; s > 0; s >>= 1) {
        if (tid < s) red[tid] = fmaxf(red[tid], red[tid + s]);
        __syncthreads();
    }
    float r = red[0] / 127.f;   // exact division, matches np max|w|/127
    __syncthreads();
    return r;
}

// Source-driven prep: coalesced linear reads, inverse-mapped scatter stores.
// grid = 220: 0..215 FD, 216 qw1+F2, 217 F3, 218 F4, 219 tail.
__global__ void __launch_bounds__(256) prep(
    const unsigned short* __restrict__ xu,
    const void* __restrict__ w1, const void* __restrict__ w2,
    const void* __restrict__ w3, const void* __restrict__ w4,
    const void* __restrict__ wd, const void* __restrict__ wo,
    const void* __restrict__ b1, const void* __restrict__ b2,
    const void* __restrict__ b3, const void* __restrict__ b4,
    const void* __restrict__ bd, const void* __restrict__ bo,
    float* __restrict__ wsf)
{
    int tid = threadIdx.x, which = blockIdx.x;
    __shared__ float red[256];
    __shared__ int cnt;
    if (tid == 0) cnt = 0;
    __syncthreads();
    int bad = 0;
    for (int i = tid; i < 2048; i += 256) {
        int e = (xu[i] >> 7) & 0xFF;      // bf16 exponent of x's halfwords
        if (e >= 147) bad = 1;            // |v| >= 2^20: x is not bf16 data
    }
    atomicAdd(&cnt, bad);
    __syncthreads();
    const int f32 = (cnt > 4) ? 1 : 0;
    h16* wh = (h16*)(wsf + 292);

    if (which < 216) {
        float sc = block_scale(wd, 55296, f32, tid, red);
        int s = which * 256 + tid;                 // 216*256 = 55296 exact
        int o = s / 864, r = s - o * 864;
        int cch = r / 27, i = r - cch * 27;
        int mt = o >> 4;
        int e = ((mt * 27 + i) * 64 + (o & 15) + (cch >> 3) * 16) * 8 + (cch & 7);
        wh[8704 + e] = (h16)qv(wd, s, sc, f32);
    } else if (which == 216) {
        float s1 = block_scale(w1, 64, f32, tid, red);
        float s2 = block_scale(w2, 768, f32, tid, red);
        for (int e = tid; e < 1024; e += 256) wh[e] = (h16)0.f;
        __syncthreads();
        if (tid < 64) wsf[tid] = qv(w1, tid, s1, f32);   // plain qw1
        for (int s = tid; s < 768; s += 256) {  // w2: s = (mm*16+ci)*3 + dk
            int mm = s / 48, r = s - mm * 48;
            int ci = r / 3, dk = r - ci * 3;
            int k = dk * 16 + ci;
            int e = (k >> 5) * 512 + (mm + ((k >> 3) & 3) * 16) * 8 + (k & 7);
            wh[e] = (h16)qv(w2, s, s2, f32);
        }
    } else if (which == 217) {
        float sc = block_scale(w3, 2560, f32, tid, red);
        for (int s = tid; s < 2560; s += 256) {
            int mm = s / 80, r = s - mm * 80;
            int ci = r / 5, dk = r - ci * 5;
            int e = (dk * 64 + mm + (ci >> 3) * 32) * 8 + (ci & 7);
            wh[1024 + e] = (h16)qv(w3, s, sc, f32);
        }
    } else if (which == 218) {
        float sc = block_scale(w4, 5120, f32, tid, red);
        for (int s = tid; s < 5120; s += 256) {
            int mm = s / 160, r = s - mm * 160;
            int ci = r / 5, dk = r - ci * 5;
            int k = dk * 32 + ci;
            int e = (k >> 4) * 512 + (mm + ((k >> 3) & 1) * 32) * 8 + (k & 7);
            wh[3584 + e] = (h16)qv(w4, s, sc, f32);
        }
    } else {
        float sc = block_scale(wo, 64, f32, tid, red);
        if (tid < 64) wsf[224 + tid] = qv(wo, tid, sc, f32);
        if (tid < 16)        wsf[64 + tid]        = ldE(b1, tid, f32);
        else if (tid < 32)   wsf[80 + tid - 16]   = ldE(b2, tid - 16, f32);
        else if (tid < 64)   wsf[96 + tid - 32]   = ldE(b3, tid - 32, f32);
        else if (tid < 96)   wsf[128 + tid - 64]  = ldE(b4, tid - 64, f32);
        else if (tid < 160)  wsf[160 + tid - 96]  = ldE(bd, tid - 96, f32);
        else if (tid == 160) wsf[288]             = ldE(bo, 0, f32);
        if (tid == 0) ((int*)wsf)[290] = f32;
    }
}

// r15 structure with conv1 moved OFF MFMA/LDS entirely: computed on VALU from
// 8 prefetched x registers (wave-uniform s_load weights), written as 4 b128
// rows straight into act1. Deletes the xi8 staging stage (+2 fences, 11 DS
// ops, 8 low-utilization MFMAs per sample-wave); VALU has headroom (33%).
__global__ void __launch_bounds__(256, 2) qcnn_main(
    const void* __restrict__ x,      // [B][2][128] bf16 or f32
    const float* __restrict__ wsf,
    void* __restrict__ out)          // [B]
{
    const int f32flag = ((const int*)wsf)[290];
    const float* qw1f = wsf;
    const float* fb1g = wsf + 64;
    const h16*  wh  = (const h16*)(wsf + 292);
    const h16*  F2g = wh;
    const h16*  F3g = wh + 1024;
    const h16*  F4g = wh + 3584;
    const h16*  FDg = wh + 8704;

    __shared__ __align__(16) h16 Uall[4][2112];   // act1 2gx132 / pooled 2gx62
    __shared__ __align__(16) h16 Vall[4][2208];   // act3 4gx69
    __shared__ __align__(16) h16 flatb[8][872];
    __shared__ float red[256];

    int tid  = threadIdx.x;
    int lane = tid & 63;
    int w    = __builtin_amdgcn_readfirstlane(tid >> 6);
    int n16  = lane & 15, kg16 = (lane >> 4) & 3;
    int n32  = lane & 31, kg32 = (lane >> 5) & 1;
    int o16  = kg16 * 4;
    h16* U = Uall[w];
    h16* V = Vall[w];
    long b0 = (long)blockIdx.x * 8;

    h16x8 a2[2], a3[5], a4[10];
#pragma unroll
    for (int c = 0; c < 2; ++c)  a2[c] = *(const h16x8*)&F2g[c * 512 + lane * 8];
#pragma unroll
    for (int c = 0; c < 5; ++c)  a3[c] = *(const h16x8*)&F3g[c * 512 + lane * 8];
#pragma unroll
    for (int c = 0; c < 10; ++c) a4[c] = *(const h16x8*)&F4g[c * 512 + lane * 8];
    f32x4 b2v = *(const f32x4*)&wsf[80 + o16];   // conv2 C-init
    f32x16 c3i, c4i;                             // conv3/4 C-init (bias rows)
#pragma unroll
    for (int g = 0; g < 4; ++g) {
        f32x4 bv3 = *(const f32x4*)&wsf[96 + 8 * g + 4 * kg32];
        f32x4 bv4 = *(const f32x4*)&wsf[128 + 8 * g + 4 * kg32];
#pragma unroll
        for (int q = 0; q < 4; ++q) { c3i[4*g+q] = bv3[q]; c4i[4*g+q] = bv4[q]; }
    }

    // prefetch both samples' x: 8 values each (ch0/ch1 at p, p+1, p2, p2+1).
    // Edge lanes: p=lane+1 etc stay in-bounds of the sample or land in rows
    // discarded by the lane<63 guard; the one potentially-OOB address (last
    // sample, ch1[p2+1] at lane 63) is wrapped with &63 (value discarded).
    float xl[2][8];
#pragma unroll
    for (int it = 0; it < 2; ++it) {
        long sb = (b0 + w * 2 + it) * 256;
        xl[it][0] = ldE(x, sb + lane, f32flag);               // ch0[p]
        xl[it][1] = ldE(x, sb + lane + 1, f32flag);           // ch0[p+1]
        xl[it][2] = ldE(x, sb + 128 + lane, f32flag);         // ch1[p]
        xl[it][3] = ldE(x, sb + 128 + lane + 1, f32flag);     // ch1[p+1]
        xl[it][4] = ldE(x, sb + 64 + lane, f32flag);          // ch0[p2]
        xl[it][5] = ldE(x, sb + 64 + lane + 1, f32flag);      // ch0[p2+1]
        xl[it][6] = ldE(x, sb + 192 + lane, f32flag);         // ch1[p2]
        xl[it][7] = ldE(x, sb + 192 + ((lane + 1) & 63), f32flag); // ch1[p2+1]
    }

#pragma unroll
    for (int it = 0; it < 2; ++it) {
        int slot = w * 2 + it;

        // ---- conv1 (VALU, register-direct): -> act1 U[2g][127] ----
        LDS_FENCE();   // order after prev iteration's U readers (conv3)
        {
#pragma unroll
            for (int g = 0; g < 2; ++g) {
                float vA[8], vB[8];
#pragma unroll
                for (int c = 0; c < 8; ++c) {
                    int co = g * 8 + c;
                    float w00 = qw1f[co*4+0], w01 = qw1f[co*4+1];
                    float w10 = qw1f[co*4+2], w11 = qw1f[co*4+3];
                    float bb  = fb1g[co];
                    vA[c] = bb + xl[it][0]*w00 + xl[it][1]*w01 + xl[it][2]*w10 + xl[it][3]*w11;
                    vB[c] = bb + xl[it][4]*w00 + xl[it][5]*w01 + xl[it][6]*w10 + xl[it][7]*w11;
                }
                uint2 pa0 = pk4l(vA[0], vA[1], vA[2], vA[3]);
                uint2 pa1 = pk4l(vA[4], vA[5], vA[6], vA[7]);
                *(uint4*)&U[g * 1056 + lane * 8] = make_uint4(pa0.x, pa0.y, pa1.x, pa1.y);
                if (lane < 63) {
                    uint2 pb0 = pk4l(vB[0], vB[1], vB[2], vB[3]);
                    uint2 pb1 = pk4l(vB[4], vB[5], vB[6], vB[7]);
                    *(uint4*)&U[g * 1056 + (64 + lane) * 8] = make_uint4(pb0.x, pb0.y, pb1.x, pb1.y);
                }
            }
        }
        if (lane < 8) {   // zero act1 pad rows 127..130 (conv2 reads n+dk<=130)
            int g = lane & 1, row = 127 + (lane >> 1);
            *(uint4*)&U[g * 1056 + row * 8] = make_uint4(0, 0, 0, 0);
        }
        LDS_FENCE();

        // ---- conv2 + FUSED pool1: act1 -> pooled U[2g][62] directly.
        //      DPP lane^1 swap + packed max; even-n lanes write row n/2.
#pragma unroll
        for (int t = 0; t < 8; ++t) {
            int n = t * 16 + n16;
            f32x4 acc = b2v;
#pragma unroll
            for (int c = 0; c < 2; ++c) {
                int k0 = c * 32 + kg16 * 8;
                int dk = k0 >> 4, g = (k0 & 15) >> 3;
                h16x8 bfr = *(const h16x8*)&U[g * 1056 + (n + dk) * 8];
                acc = __builtin_amdgcn_mfma_f32_16x16x32_f16(a2[c], bfr, acc, 0, 0, 0);
            }
            uint2 p = pk4l(acc[0], acc[1], acc[2], acc[3]);   // all lanes (DPP src)
            uint2 m = pkmax2(p, dpp_xor1(p));
            if (!(n & 1) && n < 124) {   // pooled pairs (2i,2i+1), i<62
                *(uint2*)&U[(o16 >> 3) * 1056 + (n >> 1) * 8 + (o16 & 7)] = m;
            }
        }
        LDS_FENCE();

        // ---- conv3 (32x32x16): pooled -> act3 V[4g][58] (bias in C) ----
#pragma unroll
        for (int t = 0; t < 2; ++t) {
            int n = t * 32 + n32;
            f32x16 acc = c3i;
#pragma unroll
            for (int c = 0; c < 5; ++c) {
                h16x8 bfr = *(const h16x8*)&U[kg32 * 1056 + (n + c) * 8];
                acc = __builtin_amdgcn_mfma_f32_32x32x16_f16(a3[c], bfr, acc, 0, 0, 0);
            }
            if (n < 58) {
#pragma unroll
                for (int g = 0; g < 4; ++g) {
                    *(uint2*)&V[g * 552 + n * 8 + 4 * kg32] =
                        pk4l(acc[4*g+0], acc[4*g+1], acc[4*g+2], acc[4*g+3]);
                }
            }
        }
        LDS_FENCE();

        // ---- conv4 + FUSED pool2: act3 -> flatb[slot] directly ----
#pragma unroll
        for (int t = 0; t < 2; ++t) {
            int n = t * 32 + n32;
            f32x16 acc = c4i;
#pragma unroll
            for (int c = 0; c < 10; ++c) {
                int k0 = c * 16 + kg32 * 8;
                int dk = k0 >> 5, g = (k0 >> 3) & 3;
                h16x8 bfr = *(const h16x8*)&V[g * 552 + (n + dk) * 8];
                acc = __builtin_amdgcn_mfma_f32_32x32x16_f16(a4[c], bfr, acc, 0, 0, 0);
            }
#pragma unroll
            for (int g = 0; g < 4; ++g) {
                uint2 p = pk4l(acc[4*g+0], acc[4*g+1], acc[4*g+2], acc[4*g+3]);
                uint2 m = pkmax2(p, dpp_xor1(p));
                if (!(n & 1) && n < 54) {   // pairs (2i,2i+1), i<27
                    *(uint2*)&flatb[slot][(g * 27 + (n >> 1)) * 8 + 4 * kg32] = m;
                }
            }
        }
    }
    __syncthreads();   // cross-wave: dense reads all 8 flatb slots

    // ---- dense (16x16x32): flatb[8][864] @ FD, wave w = m-tile ----
    int o0g = w * 16 + o16;
    f32x4 dacc = *(const f32x4*)&wsf[160 + o0g];  // bias in C
    for (int c = 0; c < 27; ++c) {
        h16x8 aw = *(const h16x8*)&FDg[((w * 27 + c) * 64 + lane) * 8];
        h16x8 bh = *(const h16x8*)&flatb[lane & 7][(kg16 * 27 + c) * 8];
        dacc = __builtin_amdgcn_mfma_f32_16x16x32_f16(aw, bh, dacc, 0, 0, 0);
    }
    f32x4 qov = *(const f32x4*)&wsf[224 + o0g];
    float part = 0.f;
#pragma unroll
    for (int q = 0; q < 4; ++q) part += lrelu(dacc[q]) * qov[q];
    red[tid] = part;
    __syncthreads();   // cross-wave: head reads all partials
    if (tid < 8) {
        float y = wsf[288];
#pragma unroll
        for (int g = 0; g < 16; ++g) y += red[(g >> 2) * 64 + (g & 3) * 16 + tid];
        if (f32flag) ((float*)out)[b0 + tid] = y;
        else         ((bf16*)out)[b0 + tid] = __float2bfloat16(y);
    }
}

extern "C" void kernel_launch(void* const* d_in, const int* in_sizes, int n_in,
                              void* d_out, int out_size, void* d_ws, size_t ws_size,
                              hipStream_t stream) {
    const void* x  = d_in[0];
    const void* w1 = d_in[1];
    const void* b1 = d_in[2];
    const void* w2 = d_in[3];
    const void* b2 = d_in[4];
    const void* w3 = d_in[5];
    const void* b3 = d_in[6];
    const void* w4 = d_in[7];
    const void* b4 = d_in[8];
    const void* wd = d_in[9];
    const void* bd = d_in[10];
    const void* wo = d_in[11];
    const void* bo = d_in[12];
    float* wsf = (float*)d_ws;

    int B = in_sizes[0] / 256;            // 32768
    prep<<<220, 256, 0, stream>>>((const unsigned short*)x,
                                  w1, w2, w3, w4, wd, wo,
                                  b1, b2, b3, b4, bd, bo, wsf);
    qcnn_main<<<B / 8, 256, 0, stream>>>(x, wsf, d_out);
}

// Round 17
// 178.586 us; speedup vs baseline: 1.0284x; 1.0284x over previous
//
#include <hip/hip_runtime.h>
#include <hip/hip_bf16.h>

typedef __hip_bfloat16 bf16;
typedef _Float16 h16;
typedef __attribute__((ext_vector_type(2))) _Float16 h16x2;
typedef __attribute__((ext_vector_type(2))) __fp16 fp16x2;
typedef __attribute__((ext_vector_type(8))) _Float16 h16x8;
typedef __attribute__((ext_vector_type(4))) float f32x4;
typedef __attribute__((ext_vector_type(16))) float f32x16;

__device__ __forceinline__ float lrelu(float x) { return fmaxf(x, 0.1f * x); }
__device__ __forceinline__ float ldE(const void* p, long i, int f32) {
    return f32 ? ((const float*)p)[i] : __bfloat162float(((const bf16*)p)[i]);
}
// Packed epilogue: f32x4 -> lrelu -> 4 h16 in a uint2 (cvt_pkrtz + v_pk ops).
__device__ __forceinline__ uint2 pk4l(float a, float b, float c, float d) {
    union { fp16x2 f; h16x2 h; } lo, hi;
    lo.f = __builtin_amdgcn_cvt_pkrtz(a, b);
    hi.f = __builtin_amdgcn_cvt_pkrtz(c, d);
    const h16x2 cl = {(h16)0.1f, (h16)0.1f};
    h16x2 lo2 = __builtin_elementwise_max(lo.h, lo.h * cl);
    h16x2 hi2 = __builtin_elementwise_max(hi.h, hi.h * cl);
    union { h16x2 h[2]; uint2 u; } t;
    t.h[0] = lo2; t.h[1] = hi2;
    return t.u;
}
// lane^1 swap on the VALU pipe (DPP quad_perm [1,0,3,2] = ctrl 0xB1) —
// NOT ds_swizzle/ds_bpermute (r8's shfl fusion hit the LDS pipe and lost).
__device__ __forceinline__ uint2 dpp_xor1(uint2 v) {
    uint2 r;
    r.x = (unsigned)__builtin_amdgcn_mov_dpp((int)v.x, 0xB1, 0xF, 0xF, true);
    r.y = (unsigned)__builtin_amdgcn_mov_dpp((int)v.y, 0xB1, 0xF, 0xF, true);
    return r;
}
// packed f16 max of two uint2-packed quads
__device__ __forceinline__ uint2 pkmax2(uint2 a, uint2 b) {
    union { unsigned u; h16x2 h; } ax, ay, bx, by, rx, ry;
    ax.u = a.x; ay.u = a.y; bx.u = b.x; by.u = b.y;
    rx.h = __builtin_elementwise_max(ax.h, bx.h);
    ry.h = __builtin_elementwise_max(ay.h, by.h);
    uint2 r; r.x = rx.u; r.y = ry.u;
    return r;
}
__device__ __forceinline__ unsigned umx(unsigned a, unsigned b) { return a > b ? a : b; }
// Compiler-only ordering barrier: wave-private buffers + in-order DS pipe
// (validated round 9).
#define LDS_FENCE() asm volatile("" ::: "memory")

// ---------------- workspace layout ----------------
// float region (wsf):
//   [64..79] fb1 [80..95] fb2 [96..127] fb3 [128..159] fb4
//   [160..223] fbd [224..287] qwo [288] fbo   int flag @ index 290
// f16 frag region wh = (h16*)(wsf+292):
//   F2 @0 (1024), F3 @1024 (2560), F4 @3584 (5120), FD @8704 (55296),
//   F1 @64000 (512)

__device__ __forceinline__ float qv(const void* src, int idx, float sc, int f32) {
    float w = ldE(src, idx, f32);
    float q = rintf(w / sc);                    // round-half-even like jnp.round
    return fminf(127.f, fmaxf(-127.f, q)) * sc; // clip then dequant
}

__device__ float block_scale(const void* src, int n, int f32, int tid, float* red) {
    unsigned m = 0;
    const uint4* p = (const uint4*)src;
    if (f32) {
        int nv = n >> 2;
        for (int i = tid; i < nv; i += 256) {
            uint4 u = p[i];
            m = umx(m, u.x & 0x7FFFFFFFu); m = umx(m, u.y & 0x7FFFFFFFu);
            m = umx(m, u.z & 0x7FFFFFFFu); m = umx(m, u.w & 0x7FFFFFFFu);
        }
        union { unsigned u; float f; } c; c.u = m;
        red[tid] = c.f;
    } else {
        int nv = n >> 3;
        for (int i = tid; i < nv; i += 256) {
            uint4 u = p[i];
            unsigned a;
            a = u.x & 0x7FFF7FFFu; m = umx(m, a >> 16); m = umx(m, a & 0xFFFFu);
            a = u.y & 0x7FFF7FFFu; m = umx(m, a >> 16); m = umx(m, a & 0xFFFFu);
            a = u.z & 0x7FFF7FFFu; m = umx(m, a >> 16); m = umx(m, a & 0xFFFFu);
            a = u.w & 0x7FFF7FFFu; m = umx(m, a >> 16); m = umx(m, a & 0xFFFFu);
        }
        union { unsigned u; float f; } c; c.u = m << 16;
        red[tid] = c.f;
    }
    __syncthreads();
    for (int s = 128; s > 0; s >>= 1) {
        if (tid < s) red[tid] = fmaxf(red[tid], red[tid + s]);
        __syncthreads();
    }
    float r = red[0] / 127.f;   // exact division, matches np max|w|/127
    __syncthreads();
    return r;
}

// Source-driven prep (r11): coalesced linear reads, inverse-mapped scatter
// stores. grid = 220: 0..215 FD, 216 F1+F2, 217 F3, 218 F4, 219 tail.
__global__ void __launch_bounds__(256) prep(
    const unsigned short* __restrict__ xu,
    const void* __restrict__ w1, const void* __restrict__ w2,
    const void* __restrict__ w3, const void* __restrict__ w4,
    const void* __restrict__ wd, const void* __restrict__ wo,
    const void* __restrict__ b1, const void* __restrict__ b2,
    const void* __restrict__ b3, const void* __restrict__ b4,
    const void* __restrict__ bd, const void* __restrict__ bo,
    float* __restrict__ wsf)
{
    int tid = threadIdx.x, which = blockIdx.x;
    __shared__ float red[256];
    __shared__ int cnt;
    if (tid == 0) cnt = 0;
    __syncthreads();
    int bad = 0;
    for (int i = tid; i < 2048; i += 256) {
        int e = (xu[i] >> 7) & 0xFF;      // bf16 exponent of x's halfwords
        if (e >= 147) bad = 1;            // |v| >= 2^20: x is not bf16 data
    }
    atomicAdd(&cnt, bad);
    __syncthreads();
    const int f32 = (cnt > 4) ? 1 : 0;
    h16* wh = (h16*)(wsf + 292);

    if (which < 216) {
        float sc = block_scale(wd, 55296, f32, tid, red);
        int s = which * 256 + tid;                 // 216*256 = 55296 exact
        int o = s / 864, r = s - o * 864;
        int cch = r / 27, i = r - cch * 27;
        int mt = o >> 4;
        int e = ((mt * 27 + i) * 64 + (o & 15) + (cch >> 3) * 16) * 8 + (cch & 7);
        wh[8704 + e] = (h16)qv(wd, s, sc, f32);
    } else if (which == 216) {
        float s1 = block_scale(w1, 64, f32, tid, red);
        float s2 = block_scale(w2, 768, f32, tid, red);
        for (int e = tid; e < 512; e += 256)  wh[64000 + e] = (h16)0.f;
        for (int e = tid; e < 1024; e += 256) wh[e] = (h16)0.f;
        __syncthreads();
        if (tid < 64) {    // w1[co][ci][dk]: s = co*4 + ci*2 + dk
            int s = tid, co = s >> 2, ci = (s >> 1) & 1, dk = s & 1;
            wh[64000 + (co + dk * 16) * 8 + ci] = (h16)qv(w1, s, s1, f32);
        }
        for (int s = tid; s < 768; s += 256) {  // w2: s = (mm*16+ci)*3 + dk
            int mm = s / 48, r = s - mm * 48;
            int ci = r / 3, dk = r - ci * 3;
            int k = dk * 16 + ci;
            int e = (k >> 5) * 512 + (mm + ((k >> 3) & 3) * 16) * 8 + (k & 7);
            wh[e] = (h16)qv(w2, s, s2, f32);
        }
    } else if (which == 217) {
        float sc = block_scale(w3, 2560, f32, tid, red);
        for (int s = tid; s < 2560; s += 256) {
            int mm = s / 80, r = s - mm * 80;
            int ci = r / 5, dk = r - ci * 5;
            int e = (dk * 64 + mm + (ci >> 3) * 32) * 8 + (ci & 7);
            wh[1024 + e] = (h16)qv(w3, s, sc, f32);
        }
    } else if (which == 218) {
        float sc = block_scale(w4, 5120, f32, tid, red);
        for (int s = tid; s < 5120; s += 256) {
            int mm = s / 160, r = s - mm * 160;
            int ci = r / 5, dk = r - ci * 5;
            int k = dk * 32 + ci;
            int e = (k >> 4) * 512 + (mm + ((k >> 3) & 1) * 32) * 8 + (k & 7);
            wh[3584 + e] = (h16)qv(w4, s, sc, f32);
        }
    } else {
        float sc = block_scale(wo, 64, f32, tid, red);
        if (tid < 64) wsf[224 + tid] = qv(wo, tid, sc, f32);
        if (tid < 16)        wsf[64 + tid]        = ldE(b1, tid, f32);
        else if (tid < 32)   wsf[80 + tid - 16]   = ldE(b2, tid - 16, f32);
        else if (tid < 64)   wsf[96 + tid - 32]   = ldE(b3, tid - 32, f32);
        else if (tid < 96)   wsf[128 + tid - 64]  = ldE(b4, tid - 64, f32);
        else if (tid < 160)  wsf[160 + tid - 96]  = ldE(bd, tid - 96, f32);
        else if (tid == 160) wsf[288]             = ldE(bo, 0, f32);
        if (tid == 0) ((int*)wsf)[290] = f32;
    }
}

// r15 verbatim (best measured: 92.5 µs): MFMA conv1 with xi8 staging, pools
// fused into conv2/conv4 epilogues via DPP lane^1 swap + packed f16 max,
// packed-f16 epilogues, bias-in-C, chunked conflict-free LDS layouts,
// compiler-only stage fences.
__global__ void __launch_bounds__(256, 2) qcnn_main(
    const void* __restrict__ x,      // [B][2][128] bf16 or f32
    const float* __restrict__ wsf,
    void* __restrict__ out)          // [B]
{
    const int f32flag = ((const int*)wsf)[290];
    const h16*  wh  = (const h16*)(wsf + 292);
    const h16*  F2g = wh;
    const h16*  F3g = wh + 1024;
    const h16*  F4g = wh + 3584;
    const h16*  FDg = wh + 8704;
    const h16*  F1g = wh + 64000;

    __shared__ __align__(16) h16 Uall[4][2112];   // act1 2gx132 / pooled 2gx62
    __shared__ __align__(16) h16 Vall[4][2208];   // xi8 staging / act3 4gx69
    __shared__ __align__(16) h16 flatb[8][872];
    __shared__ float red[256];

    int tid  = threadIdx.x;
    int lane = tid & 63;
    int w    = __builtin_amdgcn_readfirstlane(tid >> 6);
    int n16  = lane & 15, kg16 = (lane >> 4) & 3;
    int n32  = lane & 31, kg32 = (lane >> 5) & 1;
    int o16  = kg16 * 4;
    h16* U = Uall[w];
    h16* V = Vall[w];
    long b0 = (long)blockIdx.x * 8;

    h16x8 a1, a2[2], a3[5], a4[10];
    a1 = *(const h16x8*)&F1g[lane * 8];
#pragma unroll
    for (int c = 0; c < 2; ++c)  a2[c] = *(const h16x8*)&F2g[c * 512 + lane * 8];
#pragma unroll
    for (int c = 0; c < 5; ++c)  a3[c] = *(const h16x8*)&F3g[c * 512 + lane * 8];
#pragma unroll
    for (int c = 0; c < 10; ++c) a4[c] = *(const h16x8*)&F4g[c * 512 + lane * 8];
    f32x4 b1v = *(const f32x4*)&wsf[64 + o16];   // conv1 C-init
    f32x4 b2v = *(const f32x4*)&wsf[80 + o16];   // conv2 C-init
    f32x16 c3i, c4i;                             // conv3/4 C-init (bias rows)
#pragma unroll
    for (int g = 0; g < 4; ++g) {
        f32x4 bv3 = *(const f32x4*)&wsf[96 + 8 * g + 4 * kg32];
        f32x4 bv4 = *(const f32x4*)&wsf[128 + 8 * g + 4 * kg32];
#pragma unroll
        for (int q = 0; q < 4; ++q) { c3i[4*g+q] = bv3[q]; c4i[4*g+q] = bv4[q]; }
    }

    const h16 hz = (h16)0.f;
    const h16x8 zrow = {hz, hz, hz, hz, hz, hz, hz, hz};

    // prefetch both samples' x (global latency hidden behind it=0 compute)
    float xl[2][4];
#pragma unroll
    for (int it = 0; it < 2; ++it) {
        long sb = (b0 + w * 2 + it) * 256;
        xl[it][0] = ldE(x, sb + lane, f32flag);         // ch0, p = lane
        xl[it][1] = ldE(x, sb + 128 + lane, f32flag);   // ch1, p = lane
        xl[it][2] = ldE(x, sb + 64 + lane, f32flag);    // ch0, p = 64+lane
        xl[it][3] = ldE(x, sb + 192 + lane, f32flag);   // ch1, p = 64+lane
    }

#pragma unroll
    for (int it = 0; it < 2; ++it) {
        int slot = w * 2 + it;

        // ---- stage x as xi8 rows in V (WAR vs prev conv4 reads: in-order DS) ----
        LDS_FENCE();
        {
            h16x8 r0 = zrow, r1 = zrow;
            r0[0] = (h16)xl[it][0]; r0[1] = (h16)xl[it][1];
            r1[0] = (h16)xl[it][2]; r1[1] = (h16)xl[it][3];
            *(h16x8*)&V[lane * 8]        = r0;
            *(h16x8*)&V[(64 + lane) * 8] = r1;
            if (lane < 3) *(h16x8*)&V[(128 + lane) * 8] = zrow;
        }
        LDS_FENCE();

        // ---- conv1 (16x16x32): xi8 -> act1 U[2g][127] ----
#pragma unroll
        for (int t = 0; t < 8; ++t) {
            int n = t * 16 + n16;
            f32x4 acc = b1v;
            h16x8 bfr = *(const h16x8*)&V[(n + kg16) * 8];
            acc = __builtin_amdgcn_mfma_f32_16x16x32_f16(a1, bfr, acc, 0, 0, 0);
            if (n < 127) {
                *(uint2*)&U[(o16 >> 3) * 1056 + n * 8 + (o16 & 7)] =
                    pk4l(acc[0], acc[1], acc[2], acc[3]);
            }
        }
        if (lane < 8) {   // zero act1 pad rows 127..130
            int g = lane & 1, row = 127 + (lane >> 1);
            *(uint4*)&U[g * 1056 + row * 8] = make_uint4(0, 0, 0, 0);
        }
        LDS_FENCE();

        // ---- conv2 + FUSED pool1: act1 -> pooled U[2g][62] directly.
        //      DPP lane^1 swap + packed max; even-n lanes write row n/2.
#pragma unroll
        for (int t = 0; t < 8; ++t) {
            int n = t * 16 + n16;
            f32x4 acc = b2v;
#pragma unroll
            for (int c = 0; c < 2; ++c) {
                int k0 = c * 32 + kg16 * 8;
                int dk = k0 >> 4, g = (k0 & 15) >> 3;
                h16x8 bfr = *(const h16x8*)&U[g * 1056 + (n + dk) * 8];
                acc = __builtin_amdgcn_mfma_f32_16x16x32_f16(a2[c], bfr, acc, 0, 0, 0);
            }
            uint2 p = pk4l(acc[0], acc[1], acc[2], acc[3]);   // all lanes (DPP src)
            uint2 m = pkmax2(p, dpp_xor1(p));
            if (!(n & 1) && n < 124) {   // pooled pairs (2i,2i+1), i<62
                *(uint2*)&U[(o16 >> 3) * 1056 + (n >> 1) * 8 + (o16 & 7)] = m;
            }
        }
        LDS_FENCE();

        // ---- conv3 (32x32x16): pooled -> act3 V[4g][58] (bias in C) ----
#pragma unroll
        for (int t = 0; t < 2; ++t) {
            int n = t * 32 + n32;
            f32x16 acc = c3i;
#pragma unroll
            for (int c = 0; c < 5; ++c) {
                h16x8 bfr = *(const h16x8*)&U[kg32 * 1056 + (n + c) * 8];
                acc = __builtin_amdgcn_mfma_f32_32x32x16_f16(a3[c], bfr, acc, 0, 0, 0);
            }
            if (n < 58) {
#pragma unroll
                for (int g = 0; g < 4; ++g) {
                    *(uint2*)&V[g * 552 + n * 8 + 4 * kg32] =
                        pk4l(acc[4*g+0], acc[4*g+1], acc[4*g+2], acc[4*g+3]);
                }
            }
        }
        LDS_FENCE();

        // ---- conv4 + FUSED pool2: act3 -> flatb[slot] directly.
        //      DPP lane^1 swap + packed max; even-n lanes write fp = n/2.
#pragma unroll
        for (int t = 0; t < 2; ++t) {
            int n = t * 32 + n32;
            f32x16 acc = c4i;
#pragma unroll
            for (int c = 0; c < 10; ++c) {
                int k0 = c * 16 + kg32 * 8;
                int dk = k0 >> 5, g = (k0 >> 3) & 3;
                h16x8 bfr = *(const h16x8*)&V[g * 552 + (n + dk) * 8];
                acc = __builtin_amdgcn_mfma_f32_32x32x16_f16(a4[c], bfr, acc, 0, 0, 0);
            }
#pragma unroll
            for (int g = 0; g < 4; ++g) {
                uint2 p = pk4l(acc[4*g+0], acc[4*g+1], acc[4*g+2], acc[4*g+3]);
                uint2 m = pkmax2(p, dpp_xor1(p));
                if (!(n & 1) && n < 54) {   // pairs (2i,2i+1), i<27
                    *(uint2*)&flatb[slot][(g * 27 + (n >> 1)) * 8 + 4 * kg32] = m;
                }
            }
        }
    }
    __syncthreads();   // cross-wave: dense reads all 8 flatb slots

    // ---- dense (16x16x32): flatb[8][864] @ FD, wave w = m-tile ----
    int o0g = w * 16 + o16;
    f32x4 dacc = *(const f32x4*)&wsf[160 + o0g];  // bias in C
    for (int c = 0; c < 27; ++c) {
        h16x8 aw = *(const h16x8*)&FDg[((w * 27 + c) * 64 + lane) * 8];
        h16x8 bh = *(const h16x8*)&flatb[lane & 7][(kg16 * 27 + c) * 8];
        dacc = __builtin_amdgcn_mfma_f32_16x16x32_f16(aw, bh, dacc, 0, 0, 0);
    }
    f32x4 qov = *(const f32x4*)&wsf[224 + o0g];
    float part = 0.f;
#pragma unroll
    for (int q = 0; q < 4; ++q) part += lrelu(dacc[q]) * qov[q];
    red[tid] = part;
    __syncthreads();   // cross-wave: head reads all partials
    if (tid < 8) {
        float y = wsf[288];
#pragma unroll
        for (int g = 0; g < 16; ++g) y += red[(g >> 2) * 64 + (g & 3) * 16 + tid];
        if (f32flag) ((float*)out)[b0 + tid] = y;
        else         ((bf16*)out)[b0 + tid] = __float2bfloat16(y);
    }
}

extern "C" void kernel_launch(void* const* d_in, const int* in_sizes, int n_in,
                              void* d_out, int out_size, void* d_ws, size_t ws_size,
                              hipStream_t stream) {
    const void* x  = d_in[0];
    const void* w1 = d_in[1];
    const void* b1 = d_in[2];
    const void* w2 = d_in[3];
    const void* b2 = d_in[4];
    const void* w3 = d_in[5];
    const void* b3 = d_in[6];
    const void* w4 = d_in[7];
    const void* b4 = d_in[8];
    const void* wd = d_in[9];
    const void* bd = d_in[10];
    const void* wo = d_in[11];
    const void* bo = d_in[12];
    float* wsf = (float*)d_ws;

    int B = in_sizes[0] / 256;            // 32768
    prep<<<220, 256, 0, stream>>>((const unsigned short*)x,
                                  w1, w2, w3, w4, wd, wo,
                                  b1, b2, b3, b4, bd, bo, wsf);
    qcnn_main<<<B / 8, 256, 0, stream>>>(x, wsf, d_out);
}